// Round 3
// baseline (276.993 us; speedup 1.0000x reference)
//
#include <hip/hip_runtime.h>

// MultiScaleRoIAlign, LDS-footprint-staged, amortized schedule (round 3).
// Block = (roi, group of 8 channel-chunks of CH=8). Per block: sample params +
// staging offsets computed ONCE, then loop 8x { stage chunk -> LDS, sync,
// gather 392 outputs from LDS, sync }. Channel stride 963 (odd, =3 mod 32)
// + odd row pitch kill the round-2 bank aliasing.

#define ROI_OUT  7
#define NSAMP    14              // ROI_OUT * SR
#define C_TOT    256
#define N_PER_B  256
#define CH       8               // channels per chunk
#define GRP      8               // chunks per block
#define BLK_PER_ROI 4            // 32 chunks / GRP
#define FP_STRIDE 963            // per-channel LDS stride (odd, !=0 mod 32)
#define FP_CAP    960            // max usable floats per channel footprint
#define BINS      49

__global__ __launch_bounds__(256)
void msroi_kernel(const float* __restrict__ f0, const float* __restrict__ f1,
                  const float* __restrict__ f2, const float* __restrict__ f3,
                  const float* __restrict__ boxes, float* __restrict__ out)
{
    __shared__ float fp[CH * FP_STRIDE];   // 30.1 KB
    __shared__ int4  pY[NSAMP];            // {i0, i1, frac_bits, valid_bits}
    __shared__ int4  pX[NSAMP];

    const int tid = threadIdx.x;
    const int roi = blockIdx.x >> 2;            // / BLK_PER_ROI
    const int grp = blockIdx.x & (BLK_PER_ROI - 1);
    const int b   = roi >> 8;                   // / N_PER_B

    // ---- box + level (wave-uniform) ----
    const float* bx = boxes + (size_t)roi * 4;
    float bx1 = bx[0], by1 = bx[1], bx2 = bx[2], by2 = bx[3];

    float area = (bx2 - bx1) * (by2 - by1);
    float s    = sqrtf(area);
    float lvlf = floorf(4.0f + log2f(s * (1.0f / 224.0f)) + 1e-6f);
    lvlf = fminf(fmaxf(lvlf, 2.0f), 5.0f);
    int level = (int)lvlf - 2;

    const float* feat; int H, W; float scale;
    switch (level) {
        case 0:  feat = f0; H = 200; W = 200; scale = 0.25f;    break;
        case 1:  feat = f1; H = 100; W = 100; scale = 0.125f;   break;
        case 2:  feat = f2; H = 50;  W = 50;  scale = 0.0625f;  break;
        default: feat = f3; H = 25;  W = 25;  scale = 0.03125f; break;
    }

    float x1 = bx1 * scale, y1 = by1 * scale;
    float roi_w = fmaxf(bx2 * scale - x1, 1.0f);
    float roi_h = fmaxf(by2 * scale - y1, 1.0f);
    float bin_w = roi_w * (1.0f / ROI_OUT);
    float bin_h = roi_h * (1.0f / ROI_OUT);

    // ---- phase A: per-sample params (once per block) ----
    if (tid < 2 * NSAMP) {
        bool isy = tid >= NSAMP;
        int  j   = isy ? tid - NSAMP : tid;
        int  pb  = j >> 1, sub = j & 1;
        float start = isy ? y1 : x1;
        float bsz   = isy ? bin_h : bin_w;
        int   lim   = isy ? H : W;
        float ss = start + (float)pb * bsz + ((float)sub + 0.5f) * bsz * 0.5f;
        float v  = (ss >= -1.0f && ss <= (float)lim) ? 1.0f : 0.0f;
        float cc = fminf(fmaxf(ss, 0.0f), (float)lim - 1.0f);
        int   i0 = (int)floorf(cc);
        int   i1 = min(i0 + 1, lim - 1);
        float l  = cc - (float)i0;
        int4 pk; pk.x = i0; pk.y = i1;
        pk.z = __float_as_int(l); pk.w = __float_as_int(v);
        if (isy) pY[j] = pk; else pX[j] = pk;
    }
    __syncthreads();

    // footprint bounds read back from LDS (bitwise-consistent with params)
    const int xlo = pX[0].x, xhi = pX[NSAMP - 1].y;
    const int ylo = pY[0].x, yhi = pY[NSAMP - 1].y;
    const int fw  = xhi - xlo + 1;
    const int fh  = yhi - ylo + 1;
    const int fwp = fw | 1;
    const int fsz = fw * fh;
    const bool ok = (fwp * fh) <= FP_CAP;       // analytic bound ~900; safety

    // ---- staging offsets, once per block (<=4 rounds since fsz<=940) ----
    int dsto[4], srco[4];
    int nk = 0;
    {
        int row = tid / fw;                     // one real division
        int xx  = tid - row * fw;
        int drow = 256 / fw;
        int drx  = 256 - drow * fw;
        #pragma unroll
        for (int k = 0; k < 4; ++k) {
            int p = tid + k * 256;
            if (p < fsz) {
                dsto[k] = row * fwp + xx;
                srco[k] = row * W + xx;
                nk = k + 1;
            }
            xx += drx; row += drow;
            if (xx >= fw) { xx -= fw; row += 1; }
        }
    }

    const size_t plane_sz = (size_t)(H * W);
    const float* broi  = feat + (size_t)(b * C_TOT) * plane_sz;  // roi's image
    const float* broif = broi + (size_t)ylo * W + xlo;           // + footprint org

    for (int i = 0; i < GRP; ++i) {
        const int c0 = (grp * GRP + i) * CH;

        if (ok) {   // block-uniform
            // ---- stage CH channel footprints (coalesced) ----
            const float* base = broif + (size_t)c0 * plane_sz;
            #pragma unroll
            for (int ch = 0; ch < CH; ++ch) {
                const float* pl = base + (size_t)ch * plane_sz;
                float* d = fp + ch * FP_STRIDE;
                #pragma unroll
                for (int k = 0; k < 4; ++k)
                    if (k < nk) d[dsto[k]] = pl[srco[k]];
            }
        }
        __syncthreads();

        const int robase = (roi * C_TOT + c0) * BINS;

        if (ok) {
            // ---- gather from LDS ----
            for (int o = tid; o < CH * BINS; o += 256) {
                int ch  = o / BINS;
                int bin = o - ch * BINS;
                int ph  = bin / ROI_OUT;
                int pw  = bin - ph * ROI_OUT;
                const float* chb = fp + ch * FP_STRIDE;
                float acc = 0.0f;
                #pragma unroll
                for (int sy = 0; sy < 2; ++sy) {
                    int4 py  = pY[2 * ph + sy];
                    int  r0  = (py.x - ylo) * fwp;
                    int  r1  = (py.y - ylo) * fwp;
                    float ly = __int_as_float(py.z);
                    float vy = __int_as_float(py.w);
                    float hy = 1.0f - ly;
                    #pragma unroll
                    for (int sx = 0; sx < 2; ++sx) {
                        int4 px  = pX[2 * pw + sx];
                        int  cx0 = px.x - xlo, cx1 = px.y - xlo;
                        float lx = __int_as_float(px.z);
                        float vx = __int_as_float(px.w);
                        float hx = 1.0f - lx;
                        float v00 = chb[r0 + cx0], v01 = chb[r0 + cx1];
                        float v10 = chb[r1 + cx0], v11 = chb[r1 + cx1];
                        acc += vy * vx * (hy * (hx * v00 + lx * v01)
                                        + ly * (hx * v10 + lx * v11));
                    }
                }
                out[robase + o] = acc * 0.25f;
            }
        } else {
            // ---- fallback: direct global gather (should never trigger) ----
            const float* base = broi + (size_t)c0 * plane_sz;
            for (int o = tid; o < CH * BINS; o += 256) {
                int ch  = o / BINS;
                int bin = o - ch * BINS;
                int ph  = bin / ROI_OUT;
                int pw  = bin - ph * ROI_OUT;
                const float* plane = base + (size_t)ch * plane_sz;
                float acc = 0.0f;
                #pragma unroll
                for (int sy = 0; sy < 2; ++sy) {
                    int4 py  = pY[2 * ph + sy];
                    int  r0  = py.x * W;
                    int  r1  = py.y * W;
                    float ly = __int_as_float(py.z);
                    float vy = __int_as_float(py.w);
                    float hy = 1.0f - ly;
                    #pragma unroll
                    for (int sx = 0; sx < 2; ++sx) {
                        int4 px  = pX[2 * pw + sx];
                        float lx = __int_as_float(px.z);
                        float vx = __int_as_float(px.w);
                        float hx = 1.0f - lx;
                        float v00 = plane[r0 + px.x], v01 = plane[r0 + px.y];
                        float v10 = plane[r1 + px.x], v11 = plane[r1 + px.y];
                        acc += vy * vx * (hy * (hx * v00 + lx * v01)
                                        + ly * (hx * v10 + lx * v11));
                    }
                }
                out[robase + o] = acc * 0.25f;
            }
        }
        __syncthreads();   // fp reused next chunk
    }
}

extern "C" void kernel_launch(void* const* d_in, const int* in_sizes, int n_in,
                              void* d_out, int out_size, void* d_ws, size_t ws_size,
                              hipStream_t stream)
{
    const float* f0    = (const float*)d_in[0];
    const float* f1    = (const float*)d_in[1];
    const float* f2    = (const float*)d_in[2];
    const float* f3    = (const float*)d_in[3];
    const float* boxes = (const float*)d_in[4];
    float* out = (float*)d_out;

    dim3 grid(2 * N_PER_B * BLK_PER_ROI);   // 2048 blocks
    hipLaunchKernelGGL(msroi_kernel, grid, dim3(256), 0, stream,
                       f0, f1, f2, f3, boxes, out);
}

// Round 4
// 176.407 us; speedup vs baseline: 1.5702x; 1.5702x over previous
//
#include <hip/hip_runtime.h>
#include <hip/hip_fp16.h>

// MultiScaleRoIAlign (round 4): channels-last repack + coalesced gather.
// Pass 1: transpose pyramid [B,C,H,W] fp32 -> ws [B, hw, C] fp16 (54.4 MB),
//         LDS-tiled, coalesced on both sides.
// Pass 2: block = roi. Lane owns 4 consecutive channels; each bilinear corner
//         is ONE coalesced 8B load per lane (512B per wave). Accumulate in
//         registers, stage [c][bin] tile in LDS, write float4-coalesced.
// Fallback: if ws_size too small, round-1 direct-gather kernel (host branch).

#define ROI_OUT 7
#define NSAMP   14
#define C_TOT   256
#define N_PER_B 256
#define BINS    49
#define TOT_HW  53125          // 40000 + 10000 + 2500 + 625 per image

// hw-tile counts per level (ceil(HW/64)): 625, 157, 40, 10 -> prefix 625,782,822,832
#define NTILE_X 832

// ---------------- pass 1: transpose to channels-last fp16 ----------------
__global__ __launch_bounds__(256)
void repack_kernel(const float* __restrict__ f0, const float* __restrict__ f1,
                   const float* __restrict__ f2, const float* __restrict__ f3,
                   __half* __restrict__ ws)
{
    __shared__ float tile[64][65];

    const int tx = blockIdx.x;
    const float* feat; int HW, base;
    int hw0;
    if (tx < 625)      { feat = f0; HW = 40000; base = 0;     hw0 = tx * 64; }
    else if (tx < 782) { feat = f1; HW = 10000; base = 40000; hw0 = (tx - 625) * 64; }
    else if (tx < 822) { feat = f2; HW = 2500;  base = 50000; hw0 = (tx - 782) * 64; }
    else               { feat = f3; HW = 625;   base = 52500; hw0 = (tx - 822) * 64; }

    const int c0 = blockIdx.y * 64;
    const int b  = blockIdx.z;
    const float* src = feat + (size_t)(b * C_TOT + c0) * (size_t)HW;

    // read: wave w covers c-row (w + 4i), lanes along hw -> 256B coalesced
    const int hl  = threadIdx.x & 63;
    const int cl0 = threadIdx.x >> 6;
    const int hw  = hw0 + hl;
    if (hw < HW) {
        #pragma unroll
        for (int i = 0; i < 16; ++i) {
            int cl = cl0 + 4 * i;
            tile[cl][hl] = src[(size_t)cl * HW + hw];
        }
    }
    __syncthreads();

    // write: half2 per lane along c -> contiguous 128B per 32 lanes
    __half* dst = ws + ((size_t)b * TOT_HW + base) * C_TOT + c0;
    const int co  = (threadIdx.x & 31) * 2;
    const int ho0 = threadIdx.x >> 5;            // 0..7
    #pragma unroll
    for (int i = 0; i < 8; ++i) {
        int ho  = ho0 + 8 * i;
        int hw2 = hw0 + ho;
        if (hw2 < HW) {
            __half2 v = __floats2half2_rn(tile[co][ho], tile[co + 1][ho]);
            *(__half2*)(dst + (size_t)hw2 * C_TOT + co) = v;
        }
    }
}

// ---------------- pass 2: per-roi pooled gather ----------------
__global__ __launch_bounds__(256)
void msroi_main(const __half* __restrict__ ws, const float* __restrict__ boxes,
                float* __restrict__ out)
{
    __shared__ float oacc[C_TOT * BINS];   // [c][bin], 50176 B
    __shared__ int4  pY[NSAMP], pX[NSAMP];

    const int tid = threadIdx.x;
    const int roi = blockIdx.x;
    const int b   = roi >> 8;

    // box + level (block-uniform)
    const float* bxp = boxes + (size_t)roi * 4;
    float bx1 = bxp[0], by1 = bxp[1], bx2 = bxp[2], by2 = bxp[3];
    float area = (bx2 - bx1) * (by2 - by1);
    float s    = sqrtf(area);
    float lvlf = floorf(4.0f + log2f(s * (1.0f / 224.0f)) + 1e-6f);
    lvlf = fminf(fmaxf(lvlf, 2.0f), 5.0f);
    int level = (int)lvlf - 2;

    int H, W, lvbase; float scale;
    switch (level) {
        case 0:  H = 200; W = 200; lvbase = 0;     scale = 0.25f;    break;
        case 1:  H = 100; W = 100; lvbase = 40000; scale = 0.125f;   break;
        case 2:  H = 50;  W = 50;  lvbase = 50000; scale = 0.0625f;  break;
        default: H = 25;  W = 25;  lvbase = 52500; scale = 0.03125f; break;
    }

    float x1 = bx1 * scale, y1 = by1 * scale;
    float roi_w = fmaxf(bx2 * scale - x1, 1.0f);
    float roi_h = fmaxf(by2 * scale - y1, 1.0f);
    float bin_w = roi_w * (1.0f / ROI_OUT);
    float bin_h = roi_h * (1.0f / ROI_OUT);

    if (tid < 2 * NSAMP) {
        bool isy = tid >= NSAMP;
        int  j   = isy ? tid - NSAMP : tid;
        int  pb  = j >> 1, sub = j & 1;
        float start = isy ? y1 : x1;
        float bsz   = isy ? bin_h : bin_w;
        int   lim   = isy ? H : W;
        float ss = start + (float)pb * bsz + ((float)sub + 0.5f) * bsz * 0.5f;
        float v  = (ss >= -1.0f && ss <= (float)lim) ? 1.0f : 0.0f;
        float cc = fminf(fmaxf(ss, 0.0f), (float)lim - 1.0f);
        int   i0 = (int)floorf(cc);
        int   i1 = min(i0 + 1, lim - 1);
        float l  = cc - (float)i0;
        int4 pk; pk.x = i0; pk.y = i1;
        pk.z = __float_as_int(l); pk.w = __float_as_int(v);
        if (isy) pY[j] = pk; else pX[j] = pk;
    }
    __syncthreads();

    const int wave = tid >> 6;
    const int lane = tid & 63;
    const int c    = lane * 4;
    const __half* base = ws + ((size_t)b * TOT_HW + lvbase) * C_TOT + c;

    for (int bin = wave; bin < BINS; bin += 4) {
        int ph = bin / ROI_OUT;
        int pw = bin - ph * ROI_OUT;
        float a0 = 0.f, a1 = 0.f, a2 = 0.f, a3 = 0.f;

        #pragma unroll
        for (int sy = 0; sy < 2; ++sy) {
            int4 py  = pY[2 * ph + sy];
            float ly = __int_as_float(py.z);
            float vy = __int_as_float(py.w);
            float hy = 1.0f - ly;
            #pragma unroll
            for (int sx = 0; sx < 2; ++sx) {
                int4 px  = pX[2 * pw + sx];
                float lx = __int_as_float(px.z);
                float vv = vy * __int_as_float(px.w);
                float hx = 1.0f - lx;
                float w00 = vv * hy * hx, w01 = vv * hy * lx;
                float w10 = vv * ly * hx, w11 = vv * ly * lx;

                const __half2* p00 = (const __half2*)(base + (size_t)(py.x * W + px.x) * C_TOT);
                const __half2* p01 = (const __half2*)(base + (size_t)(py.x * W + px.y) * C_TOT);
                const __half2* p10 = (const __half2*)(base + (size_t)(py.y * W + px.x) * C_TOT);
                const __half2* p11 = (const __half2*)(base + (size_t)(py.y * W + px.y) * C_TOT);

                float2 g0, g1;
                g0 = __half22float2(p00[0]); g1 = __half22float2(p00[1]);
                a0 += w00 * g0.x; a1 += w00 * g0.y; a2 += w00 * g1.x; a3 += w00 * g1.y;
                g0 = __half22float2(p01[0]); g1 = __half22float2(p01[1]);
                a0 += w01 * g0.x; a1 += w01 * g0.y; a2 += w01 * g1.x; a3 += w01 * g1.y;
                g0 = __half22float2(p10[0]); g1 = __half22float2(p10[1]);
                a0 += w10 * g0.x; a1 += w10 * g0.y; a2 += w10 * g1.x; a3 += w10 * g1.y;
                g0 = __half22float2(p11[0]); g1 = __half22float2(p11[1]);
                a0 += w11 * g0.x; a1 += w11 * g0.y; a2 += w11 * g1.x; a3 += w11 * g1.y;
            }
        }
        oacc[(c + 0) * BINS + bin] = a0 * 0.25f;
        oacc[(c + 1) * BINS + bin] = a1 * 0.25f;
        oacc[(c + 2) * BINS + bin] = a2 * 0.25f;
        oacc[(c + 3) * BINS + bin] = a3 * 0.25f;
    }
    __syncthreads();

    // coalesced writeout: [c][bin] tile -> out[roi][c][7][7]
    float4*       o4 = (float4*)(out + (size_t)roi * (C_TOT * BINS));
    const float4* s4 = (const float4*)oacc;
    for (int j = tid; j < (C_TOT * BINS) / 4; j += 256) o4[j] = s4[j];
}

// ---------------- fallback: round-1 direct gather ----------------
__global__ __launch_bounds__(256)
void msroi_direct(const float* __restrict__ f0, const float* __restrict__ f1,
                  const float* __restrict__ f2, const float* __restrict__ f3,
                  const float* __restrict__ boxes, float* __restrict__ out, int total)
{
    int e = blockIdx.x * 256 + threadIdx.x;
    if (e >= total) return;
    int bin = e % BINS;
    int c   = (e / BINS) % C_TOT;
    int roi = e / (BINS * C_TOT);
    int b   = roi / N_PER_B;

    const float* bx = boxes + (size_t)roi * 4;
    float bx1 = bx[0], by1 = bx[1], bx2 = bx[2], by2 = bx[3];
    float area = (bx2 - bx1) * (by2 - by1);
    float s    = sqrtf(area);
    float lvlf = floorf(4.0f + log2f(s * (1.0f / 224.0f)) + 1e-6f);
    lvlf = fminf(fmaxf(lvlf, 2.0f), 5.0f);
    int level = (int)lvlf - 2;

    const float* feat; int H, W; float scale;
    switch (level) {
        case 0:  feat = f0; H = 200; W = 200; scale = 0.25f;    break;
        case 1:  feat = f1; H = 100; W = 100; scale = 0.125f;   break;
        case 2:  feat = f2; H = 50;  W = 50;  scale = 0.0625f;  break;
        default: feat = f3; H = 25;  W = 25;  scale = 0.03125f; break;
    }
    float x1 = bx1 * scale, y1 = by1 * scale;
    float roi_w = fmaxf(bx2 * scale - x1, 1.0f);
    float roi_h = fmaxf(by2 * scale - y1, 1.0f);
    float bin_w = roi_w * (1.0f / ROI_OUT);
    float bin_h = roi_h * (1.0f / ROI_OUT);
    int ph = bin / ROI_OUT, pw = bin - ph * ROI_OUT;
    const float* plane = feat + ((size_t)(b * C_TOT + c)) * (size_t)(H * W);
    float Hf = (float)H, Wf = (float)W, acc = 0.0f;
    #pragma unroll
    for (int sy = 0; sy < 2; ++sy) {
        float ys = y1 + (float)ph * bin_h + ((float)sy + 0.5f) * bin_h * 0.5f;
        float vy = (ys >= -1.0f && ys <= Hf) ? 1.0f : 0.0f;
        float y  = fminf(fmaxf(ys, 0.0f), Hf - 1.0f);
        int   y0 = (int)floorf(y);
        int   y1i = min(y0 + 1, H - 1);
        float ly = y - (float)y0, hy = 1.0f - ly;
        int ro0 = y0 * W, ro1 = y1i * W;
        #pragma unroll
        for (int sx = 0; sx < 2; ++sx) {
            float xs = x1 + (float)pw * bin_w + ((float)sx + 0.5f) * bin_w * 0.5f;
            float vx = (xs >= -1.0f && xs <= Wf) ? 1.0f : 0.0f;
            float x  = fminf(fmaxf(xs, 0.0f), Wf - 1.0f);
            int   x0 = (int)floorf(x);
            int   x1i = min(x0 + 1, W - 1);
            float lx = x - (float)x0, hx = 1.0f - lx;
            float v00 = plane[ro0 + x0],  v01 = plane[ro0 + x1i];
            float v10 = plane[ro1 + x0],  v11 = plane[ro1 + x1i];
            acc += vy * vx * (hy * (hx * v00 + lx * v01) + ly * (hx * v10 + lx * v11));
        }
    }
    out[e] = acc * 0.25f;
}

extern "C" void kernel_launch(void* const* d_in, const int* in_sizes, int n_in,
                              void* d_out, int out_size, void* d_ws, size_t ws_size,
                              hipStream_t stream)
{
    const float* f0    = (const float*)d_in[0];
    const float* f1    = (const float*)d_in[1];
    const float* f2    = (const float*)d_in[2];
    const float* f3    = (const float*)d_in[3];
    const float* boxes = (const float*)d_in[4];
    float* out = (float*)d_out;

    const size_t ws_needed = (size_t)2 * TOT_HW * C_TOT * sizeof(__half); // 54.4 MB
    if (ws_size >= ws_needed) {
        __half* ws = (__half*)d_ws;
        hipLaunchKernelGGL(repack_kernel, dim3(NTILE_X, 4, 2), dim3(256), 0, stream,
                           f0, f1, f2, f3, ws);
        hipLaunchKernelGGL(msroi_main, dim3(2 * N_PER_B), dim3(256), 0, stream,
                           ws, boxes, out);
    } else {
        int total = out_size;
        hipLaunchKernelGGL(msroi_direct, dim3((total + 255) / 256), dim3(256), 0, stream,
                           f0, f1, f2, f3, boxes, out, total);
    }
}